// Round 1
// baseline (1143.167 us; speedup 1.0000x reference)
//
#include <hip/hip_runtime.h>
#include <math.h>

#define B_ 8
#define N_ 50000
#define L_ 512
#define R_ 5
#define H1_ 200
#define H2_ 100
#define C_ 2

// ---------------------------------------------------------------------------
// Kernel 1: scores[b,n] = dot(x[b,n,:], conv_w) + conv_b
// One wave (64 lanes) per instance; 2 x float4 per lane = 512 floats / wave.
// ---------------------------------------------------------------------------
__global__ __launch_bounds__(256) void chowder_scores(
    const float* __restrict__ x,
    const float* __restrict__ conv_w,
    const float* __restrict__ conv_b,
    float* __restrict__ scores)
{
    const int lane = threadIdx.x & 63;
    const float4* cw4 = reinterpret_cast<const float4*>(conv_w);
    const float4 cw0 = cw4[lane];        // conv_w[4*lane .. 4*lane+4)
    const float4 cw1 = cw4[64 + lane];   // conv_w[256+4*lane .. )
    const float cb = conv_b[0];

    const int total  = B_ * N_;
    const int gwave  = (blockIdx.x * blockDim.x + threadIdx.x) >> 6;
    const int nwaves = (gridDim.x * blockDim.x) >> 6;

    for (int inst = gwave; inst < total; inst += nwaves) {
        const float4* xp = reinterpret_cast<const float4*>(x + (size_t)inst * L_);
        float4 a = xp[lane];       // elements [4*lane, 4*lane+4)
        float4 b = xp[64 + lane];  // elements [256+4*lane, ...)
        float s = a.x * cw0.x + a.y * cw0.y + a.z * cw0.z + a.w * cw0.w
                + b.x * cw1.x + b.y * cw1.y + b.z * cw1.z + b.w * cw1.w;
        #pragma unroll
        for (int off = 32; off >= 1; off >>= 1)
            s += __shfl_xor(s, off, 64);
        if (lane == 0) scores[inst] = s + cb;
    }
}

// ---------------------------------------------------------------------------
// Kernel 2: per-batch top-R / bottom-R + tiny MLP. One block per batch.
// All top-k lists use static-index insertion (stays in registers).
// ---------------------------------------------------------------------------
__global__ __launch_bounds__(256) void chowder_topk_mlp(
    const float* __restrict__ scores,
    const float* __restrict__ w1, const float* __restrict__ b1,
    const float* __restrict__ w2, const float* __restrict__ b2,
    const float* __restrict__ w3, const float* __restrict__ b3,
    float* __restrict__ out)
{
    __shared__ float smax[256][R_];
    __shared__ float smin[256][R_];
    __shared__ float cat[2 * R_];
    __shared__ float h1[H1_];
    __shared__ float h2[H2_];

    const int b   = blockIdx.x;
    const int tid = threadIdx.x;
    const float* sc = scores + b * N_;

    // thread-local sorted lists: tmax descending, tmin ascending
    float tmax[R_], tmin[R_];
    #pragma unroll
    for (int i = 0; i < R_; ++i) { tmax[i] = -INFINITY; tmin[i] = INFINITY; }

    for (int i = tid; i < N_; i += 256) {
        float v = sc[i];
        if (v > tmax[R_ - 1]) {
            tmax[R_ - 1] = v;
            #pragma unroll
            for (int k = R_ - 1; k > 0; --k)
                if (tmax[k] > tmax[k - 1]) { float t = tmax[k]; tmax[k] = tmax[k - 1]; tmax[k - 1] = t; }
        }
        if (v < tmin[R_ - 1]) {
            tmin[R_ - 1] = v;
            #pragma unroll
            for (int k = R_ - 1; k > 0; --k)
                if (tmin[k] < tmin[k - 1]) { float t = tmin[k]; tmin[k] = tmin[k - 1]; tmin[k - 1] = t; }
        }
    }

    #pragma unroll
    for (int i = 0; i < R_; ++i) { smax[tid][i] = tmax[i]; smin[tid][i] = tmin[i]; }
    __syncthreads();

    // tree merge: partner's 5 values inserted into our register lists
    for (int half = 128; half >= 1; half >>= 1) {
        if (tid < half) {
            #pragma unroll
            for (int j = 0; j < R_; ++j) {
                float v = smax[tid + half][j];
                if (v > tmax[R_ - 1]) {
                    tmax[R_ - 1] = v;
                    #pragma unroll
                    for (int k = R_ - 1; k > 0; --k)
                        if (tmax[k] > tmax[k - 1]) { float t = tmax[k]; tmax[k] = tmax[k - 1]; tmax[k - 1] = t; }
                }
                v = smin[tid + half][j];
                if (v < tmin[R_ - 1]) {
                    tmin[R_ - 1] = v;
                    #pragma unroll
                    for (int k = R_ - 1; k > 0; --k)
                        if (tmin[k] < tmin[k - 1]) { float t = tmin[k]; tmin[k] = tmin[k - 1]; tmin[k - 1] = t; }
                }
            }
            #pragma unroll
            for (int i = 0; i < R_; ++i) { smax[tid][i] = tmax[i]; smin[tid][i] = tmin[i]; }
        }
        __syncthreads();
    }

    if (tid == 0) {
        // cat = [min ascending (R), max descending (R)]
        #pragma unroll
        for (int i = 0; i < R_; ++i) { cat[i] = tmin[i]; cat[R_ + i] = tmax[i]; }
    }
    __syncthreads();

    // MLP: 10 -> 200 -> 100 -> 2 (no activations)
    if (tid < H1_) {
        float s = b1[tid];
        #pragma unroll
        for (int i = 0; i < 2 * R_; ++i) s += cat[i] * w1[i * H1_ + tid];
        h1[tid] = s;
    }
    __syncthreads();
    if (tid < H2_) {
        float s = b2[tid];
        for (int k = 0; k < H1_; ++k) s += h1[k] * w2[k * H2_ + tid];
        h2[tid] = s;
    }
    __syncthreads();
    if (tid < C_) {
        float s = b3[tid];
        for (int k = 0; k < H2_; ++k) s += h2[k] * w3[k * C_ + tid];
        out[b * C_ + tid] = s;
    }
}

// ---------------------------------------------------------------------------
extern "C" void kernel_launch(void* const* d_in, const int* in_sizes, int n_in,
                              void* d_out, int out_size, void* d_ws, size_t ws_size,
                              hipStream_t stream) {
    const float* x      = (const float*)d_in[0];
    const float* conv_w = (const float*)d_in[1];
    const float* conv_b = (const float*)d_in[2];
    const float* w1     = (const float*)d_in[3];
    const float* b1     = (const float*)d_in[4];
    const float* w2     = (const float*)d_in[5];
    const float* b2     = (const float*)d_in[6];
    const float* w3     = (const float*)d_in[7];
    const float* b3     = (const float*)d_in[8];
    float* out = (float*)d_out;

    float* scores = (float*)d_ws;  // B_*N_ floats = 1.6 MB

    chowder_scores<<<2048, 256, 0, stream>>>(x, conv_w, conv_b, scores);
    chowder_topk_mlp<<<B_, 256, 0, stream>>>(scores, w1, b1, w2, b2, w3, b3, out);
}